// Round 7
// baseline (275.466 us; speedup 1.0000x reference)
//
#include <hip/hip_runtime.h>
#include <stdint.h>
#include <utility>

// ---------------- problem constants ----------------
#define NPTS   262144      // 4 * 65536
#define GXGY   140800      // 352*400
#define GYv    400
#define NSEG   563201      // 4*GXGY + 1
#define SENT   563200
#define NB_SCAN 275        // 563200 / 2048
#define PIL_BLOCKS 2048    // persistent k_pillar grid
#define CNT_CHUNKS 512     // k_count chunks (512 points each); grid = 2x
#define PC_BLOCKS  512     // k_pilcorr grid

// ---------------- ws layout (bytes) ----------------
// Zeroed prefix: cnt + mom + done (one ~2.26 MB memset)
constexpr size_t alignup(size_t x) { return (x + 255) & ~(size_t)255; }
constexpr size_t O_CNT  = 0;                                   // NSEG u32 (zeroed)
constexpr size_t O_MOM  = alignup(O_CNT + (size_t)NSEG * 4);   // 104 f32 (zeroed)
constexpr size_t O_DONE = alignup(O_MOM + 104 * 4);            // 1 u32 (zeroed)
constexpr size_t ZERO_BYTES = alignup(O_DONE + 256);
constexpr size_t O_PPTR = ZERO_BYTES;                          // NSEG u32 (sort cursor)
constexpr size_t O_ROWI = alignup(O_PPTR + (size_t)NSEG * 4);  // NPTS uint4 (rank -> id,start,n)
constexpr size_t O_FEAT = alignup(O_ROWI + (size_t)NPTS * 16); // NPTS*8 f32 (sorted raw feats)
constexpr size_t O_MEAN = alignup(O_FEAT + (size_t)NPTS * 32); // NPTS*3 f32 (per-rank mean)
constexpr size_t O_BSO  = alignup(O_MEAN + (size_t)NPTS * 12); // NB_SCAN u32 occ block sums
constexpr size_t O_BSC  = alignup(O_BSO + NB_SCAN * 4);        // NB_SCAN u32 cnt block sums
constexpr size_t O_KP   = alignup(O_BSC + NB_SCAN * 4);        // 1 u32 (#real pillars)
constexpr size_t O_WF   = alignup(O_KP + 256);                 // 832 f32: W*scale folded
constexpr size_t O_SH   = alignup(O_WF + 832 * 4);             // 64 f32: shift

// binning: mirror reference f32 arithmetic exactly (division, trunc, compares)
__device__ __forceinline__ int point_lin(float x, float y, int b, bool& mask) {
  float cxf = x / 0.2f;
  float cyf = (y + 40.0f) / 0.2f;
  int cx = (int)cxf, cy = (int)cyf;
  mask = (cxf >= 0.0f) && (cxf < 352.0f) && (cyf >= 0.0f) && (cyf < 400.0f);
  return mask ? (b * GXGY + cx * GYv + cy) : SENT;
}

// ---------------- K1: count + raw moments, template-split (spill fix) ----------------
// R6 post-mortem: a single 65-float accumulator array spilled to scratch
// (R4 counters: VGPR_Count=16 => demoted). Split slots across block-parity
// halves: G=0 handles rix 0..32 + the cnt atomics; G=1 handles rix 33..64.
// ~33 accumulators/instance fits VGPRs. pts read twice (+1.5us streamed).
template<int LO, int NC, bool DOCNT>
__device__ __forceinline__ void count_body(const float* __restrict__ pts,
                                           unsigned int* __restrict__ cnt,
                                           float* __restrict__ mom,
                                           int chunk) {
  int tid = threadIdx.x;
  float acc[NC];
#pragma unroll
  for (int u = 0; u < NC; u++) acc[u] = 0.f;

  for (int rep = 0; rep < 2; rep++) {
    int i = chunk * 512 + rep * 256 + tid;
    const float* p = pts + (size_t)i * 7;
    float x = p[0], y = p[1], z = p[2];
    float w3 = p[3], w4 = p[4], w5 = p[5], w6 = p[6];
    if (DOCNT) {
      bool m;
      int lin = point_lin(x, y, i >> 16, m);
      atomicAdd(&cnt[lin], 1u);
    }
    int cx = (int)(x / 0.2f);
    int cy = (int)((y + 40.0f) / 0.2f);
    int cz = (int)((z + 3.0f) / 4.0f);
    float g[10] = {x, y, z, w3, w4, w5, w6,
                   x - ((float)cx * 0.2f + 0.1f + 0.0f),
                   y - ((float)cy * 0.2f + 0.1f - 40.0f),
                   z - ((float)cz * 4.0f + 2.0f - 3.0f)};
    int idx = 0;
#pragma unroll
    for (int q = 0; q < 10; q++) {
      if (idx >= LO && idx < LO + NC) acc[idx - LO] += g[q];
      idx++;
    }
#pragma unroll
    for (int pp = 0; pp < 10; pp++)
#pragma unroll
      for (int q = pp; q < 10; q++) {
        if (idx >= LO && idx < LO + NC) acc[idx - LO] += g[pp] * g[q];
        idx++;
      }
  }

  __shared__ float red[4][NC];
  int wv = tid >> 6, lane = tid & 63;
#pragma unroll
  for (int u = 0; u < NC; u++) {
    float v = acc[u];
    v += __shfl_xor(v, 1);  v += __shfl_xor(v, 2);  v += __shfl_xor(v, 4);
    v += __shfl_xor(v, 8);  v += __shfl_xor(v, 16); v += __shfl_xor(v, 32);
    if (lane == 0) red[wv][u] = v;
  }
  __syncthreads();
  int t = tid;
  if (t < 104 && !(t >= 7 && t <= 9)) {   // S1 u-slots come only from corrections
    int rix;
    if (t < 13) {
      rix = (t < 7) ? t : t - 3;          // phi: 10..12 -> 7..9 (c feats)
    } else {
      int u2 = t - 13, j = 0;
      while (u2 >= 13 - j) { u2 -= 13 - j; j++; }
      int k = j + u2;
      int a = (j < 7) ? j : (j < 10 ? j - 7 : j - 3);
      int b = (k < 7) ? k : (k < 10 ? k - 7 : k - 3);
      int lo = a < b ? a : b, hi = a < b ? b : a;
      rix = 10 + lo * (21 - lo) / 2 + (hi - lo);
    }
    if (rix >= LO && rix < LO + NC)
      atomicAdd(&mom[t], red[0][rix - LO] + red[1][rix - LO] +
                         red[2][rix - LO] + red[3][rix - LO]);
  }
}

__global__ __launch_bounds__(256) void k_count(const float* __restrict__ pts,
                                               unsigned int* __restrict__ cnt,
                                               float* __restrict__ mom) {
  int chunk = blockIdx.x >> 1;
  if ((blockIdx.x & 1) == 0) count_body<0, 33, true >(pts, cnt, mom, chunk);
  else                       count_body<33, 32, false>(pts, cnt, mom, chunk);
}

// ---------------- K2: per-block occupancy/count sums ----------------
__global__ __launch_bounds__(256) void k_scan1(const unsigned int* __restrict__ cnt,
                                               unsigned int* __restrict__ bso,
                                               unsigned int* __restrict__ bsc) {
  int t = threadIdx.x;
  int base = blockIdx.x * 2048 + t * 8;
  const uint4* c4 = (const uint4*)(cnt + base);
  uint4 a = c4[0], b = c4[1];
  unsigned so = (a.x > 0) + (a.y > 0) + (a.z > 0) + (a.w > 0) +
                (b.x > 0) + (b.y > 0) + (b.z > 0) + (b.w > 0);
  unsigned sc = a.x + a.y + a.z + a.w + b.x + b.y + b.z + b.w;
  for (int m = 1; m < 64; m <<= 1) { so += __shfl_xor(so, m); sc += __shfl_xor(sc, m); }
  __shared__ unsigned wo[4], wc[4];
  if ((t & 63) == 0) { wo[t >> 6] = so; wc[t >> 6] = sc; }
  __syncthreads();
  if (t == 0) {
    bso[blockIdx.x] = wo[0] + wo[1] + wo[2] + wo[3];
    bsc[blockIdx.x] = wc[0] + wc[1] + wc[2] + wc[3];
  }
}

// ---------------- K3: ranks + rowinfo + sort-cursor ----------------
__global__ __launch_bounds__(256) void k_scan3(const unsigned int* __restrict__ cnt,
                                               const unsigned int* __restrict__ bso,
                                               const unsigned int* __restrict__ bsc,
                                               uint4* __restrict__ rowinfo,
                                               unsigned int* __restrict__ pptr,
                                               unsigned int* __restrict__ kp) {
  int t = threadIdx.x;
  unsigned vo_m = 0, vc_m = 0, vo_a = 0;
  for (int e = t; e < NB_SCAN; e += 256) {
    unsigned o = bso[e], c = bsc[e];
    vo_a += o;
    if (e < (int)blockIdx.x) { vo_m += o; vc_m += c; }
  }
  for (int m = 1; m < 64; m <<= 1) {
    vo_m += __shfl_xor(vo_m, m);
    vc_m += __shfl_xor(vc_m, m);
    vo_a += __shfl_xor(vo_a, m);
  }
  __shared__ unsigned s0[4], s1[4], s2[4];
  int wv = t >> 6;
  if ((t & 63) == 0) { s0[wv] = vo_m; s1[wv] = vc_m; s2[wv] = vo_a; }
  __syncthreads();
  unsigned boo = s0[0] + s0[1] + s0[2] + s0[3];
  unsigned boc = s1[0] + s1[1] + s1[2] + s1[3];
  unsigned tot = s2[0] + s2[1] + s2[2] + s2[3];
  if (blockIdx.x == 0 && t == 0) *kp = tot;

  int base = blockIdx.x * 2048 + t * 8;
  const uint4* q = (const uint4*)(cnt + base);
  uint4 a = q[0], b = q[1];
  unsigned c[8] = {a.x, a.y, a.z, a.w, b.x, b.y, b.z, b.w};
  unsigned po[8], pc[8];
  unsigned so = 0, sc = 0;
#pragma unroll
  for (int k = 0; k < 8; k++) {
    po[k] = so; pc[k] = sc;
    so += (c[k] > 0); sc += c[k];
  }
  __shared__ unsigned sdo[256], sdc[256];
  __syncthreads();
  sdo[t] = so; sdc[t] = sc;
  __syncthreads();
  for (int off = 1; off < 256; off <<= 1) {
    unsigned ao = (t >= off) ? sdo[t - off] : 0u;
    unsigned ac = (t >= off) ? sdc[t - off] : 0u;
    __syncthreads();
    sdo[t] += ao; sdc[t] += ac;
    __syncthreads();
  }
  unsigned eo = sdo[t] - so + boo;
  unsigned ec = sdc[t] - sc + boc;
#pragma unroll
  for (int k = 0; k < 8; k++) {
    if (c[k] > 0) {
      unsigned r = eo + po[k];
      unsigned start = ec + pc[k];
      rowinfo[r] = make_uint4((unsigned)(base + k), start, c[k], 0u);
      pptr[base + k] = start;
    }
  }
}

// ---------------- K4: counting-sort of RAW features only (8 f32/row) ----------------
__global__ __launch_bounds__(256) void k_sortfeat(const float* __restrict__ pts,
                                                  unsigned int* __restrict__ pptr,
                                                  float* __restrict__ feat) {
  int i = blockIdx.x * 256 + threadIdx.x;
  if (i >= NPTS) return;
  const float* p = pts + (size_t)i * 7;
  float x = p[0], y = p[1], z = p[2];
  bool m;
  int lin = point_lin(x, y, i >> 16, m);
  if (lin == SENT) return;
  unsigned pos = atomicAdd(&pptr[lin], 1u);
  float4* fb = (float4*)(feat + (size_t)pos * 8);
  fb[0] = make_float4(x, y, z, p[3]);
  fb[1] = make_float4(p[4], p[5], p[6], 0.0f);
}

// ---------------- K5: per-pillar corrections + meanr + fused BN finalize ----------------
__global__ __launch_bounds__(256) void k_pilcorr(const uint4* __restrict__ rowinfo,
                                                 const float* __restrict__ feat,
                                                 const unsigned int* __restrict__ kpp,
                                                 float* __restrict__ mom,
                                                 float* __restrict__ meanr,
                                                 unsigned int* __restrict__ done,
                                                 const float* __restrict__ W,
                                                 const float* __restrict__ g,
                                                 const float* __restrict__ bta,
                                                 float* __restrict__ wf,
                                                 float* __restrict__ sh) {
  int tid = threadIdx.x;
  unsigned kp = *kpp;
  float cS1[3] = {0.f, 0.f, 0.f};
  float cAH[30], cUU[6];
#pragma unroll
  for (int u = 0; u < 30; u++) cAH[u] = 0.f;
#pragma unroll
  for (int u = 0; u < 6; u++) cUU[u] = 0.f;

  for (unsigned r = blockIdx.x * 256 + tid; r < kp; r += PC_BLOCKS * 256) {
    uint4 ri = rowinfo[r];
    unsigned start = ri.y, n = ri.z;
    const float4* fp = (const float4*)(feat + (size_t)start * 8);
    float S[10];
#pragma unroll
    for (int u = 0; u < 10; u++) S[u] = 0.f;
    for (unsigned p = 0; p < n; p++) {
      float4 A = fp[2 * p], Bq = fp[2 * p + 1];
      float x = A.x, y = A.y, z = A.z;
      int cx = (int)(x / 0.2f);
      int cy = (int)((y + 40.0f) / 0.2f);
      int cz = (int)((z + 3.0f) / 4.0f);
      S[0] += x; S[1] += y; S[2] += z; S[3] += A.w;
      S[4] += Bq.x; S[5] += Bq.y; S[6] += Bq.z;
      S[7] += x - ((float)cx * 0.2f + 0.1f + 0.0f);
      S[8] += y - ((float)cy * 0.2f + 0.1f - 40.0f);
      S[9] += z - ((float)cz * 4.0f + 2.0f - 3.0f);
    }
    float fn = (float)n;
    float mm[3] = {S[0] / fn, S[1] / fn, S[2] / fn};
    meanr[(size_t)r * 3 + 0] = mm[0];
    meanr[(size_t)r * 3 + 1] = mm[1];
    meanr[(size_t)r * 3 + 2] = mm[2];
    cS1[0] += S[0] - fn * mm[0];
    cS1[1] += S[1] - fn * mm[1];
    cS1[2] += S[2] - fn * mm[2];
#pragma unroll
    for (int a = 0; a < 3; a++)
#pragma unroll
      for (int h = 0; h < 10; h++) cAH[a * 10 + h] += mm[a] * S[h];
    int e = 0;
#pragma unroll
    for (int a = 0; a < 3; a++)
#pragma unroll
      for (int b = a; b < 3; b++) { cUU[e] += mm[a] * S[b]; e++; }
  }

  float vals[39];
#pragma unroll
  for (int u = 0; u < 3; u++)  vals[u] = cS1[u];
#pragma unroll
  for (int u = 0; u < 30; u++) vals[3 + u] = cAH[u];
#pragma unroll
  for (int u = 0; u < 6; u++)  vals[33 + u] = cUU[u];

  __shared__ float red[4][39];
  int wv = tid >> 6, lane = tid & 63;
#pragma unroll
  for (int u = 0; u < 39; u++) {
    float v = vals[u];
    v += __shfl_xor(v, 1);  v += __shfl_xor(v, 2);  v += __shfl_xor(v, 4);
    v += __shfl_xor(v, 8);  v += __shfl_xor(v, 16); v += __shfl_xor(v, 32);
    if (lane == 0) red[wv][u] = v;
  }
  __syncthreads();
  if (tid < 39) {
    float v = red[0][tid] + red[1][tid] + red[2][tid] + red[3][tid];
    int slot; float sign;
    if (tid < 3) {
      slot = 7 + tid; sign = 1.f;
    } else if (tid < 33) {
      int a = (tid - 3) / 10, h = (tid - 3) % 10;
      int hf = (h < 7) ? h : h + 3;
      int j = hf < 7 + a ? hf : 7 + a;
      int k = hf < 7 + a ? 7 + a : hf;
      slot = 13 + j * (27 - j) / 2 + (k - j);
      sign = -1.f;
    } else {
      int e = tid - 33;  // (0,0)(0,1)(0,2)(1,1)(1,2)(2,2)
      int a = (e < 3) ? 0 : (e < 5 ? 1 : 2);
      int b = (e < 3) ? e : (e < 5 ? e - 2 : 2);
      int j = 7 + a, k = 7 + b;
      slot = 13 + j * (27 - j) / 2 + (k - j);
      sign = -1.f;
    }
    atomicAdd(&mom[slot], sign * v);
  }

  // ---- last-block BN finalize (fence+counter; verified in R2) ----
  __threadfence();
  __syncthreads();
  __shared__ unsigned lastf;
  if (tid == 0) lastf = (atomicAdd(done, 1u) == PC_BLOCKS - 1);
  __syncthreads();
  if (lastf) {
    __shared__ float smom[104];
    for (int u = tid; u < 104; u += 256) smom[u] = atomicAdd(&mom[u], 0.0f);  // coherent read
    __syncthreads();
    if (tid < 64) {
      int c = tid;
      float w[13];
#pragma unroll
      for (int j = 0; j < 13; j++) w[j] = W[c * 13 + j];
      const float invN = 1.0f / (float)NPTS;
      float mu = 0.f;
#pragma unroll
      for (int j = 0; j < 13; j++) mu += w[j] * (smom[j] * invN);
      float e2 = 0.f;
      int mi = 13;
#pragma unroll
      for (int j = 0; j < 13; j++) {
#pragma unroll
        for (int k = j; k < 13; k++) {
          float coef = (j == k) ? 1.0f : 2.0f;
          e2 += coef * w[j] * w[k] * smom[mi];
          mi++;
        }
      }
      e2 *= invN;
      float var = e2 - mu * mu;
      float rsig = 1.0f / sqrtf(var + 1e-3f);
      float sc = g[c] * rsig;
#pragma unroll
      for (int j = 0; j < 13; j++) wf[c * 13 + j] = w[j] * sc;
      sh[c] = bta[c] - mu * sc;
    }
  }
}

// ---------------- K6: per-pillar PFN + max, split real/empty phases ----------------
__global__ __launch_bounds__(256) void k_pillar(const float* __restrict__ wf,
                                                const float* __restrict__ sh,
                                                const uint4* __restrict__ rowinfo,
                                                const unsigned int* __restrict__ kp_p,
                                                const float* __restrict__ feat,
                                                const float* __restrict__ meanr,
                                                float* __restrict__ out) {
  int tid = threadIdx.x;
  int lane = tid & 15;
  int ch0 = lane * 4;
  float wr[52];
  float shv[4], wx[4], wy[4], wz[4];
#pragma unroll
  for (int c4 = 0; c4 < 4; c4++) {
    shv[c4] = sh[ch0 + c4];
#pragma unroll
    for (int j = 0; j < 13; j++) wr[c4 * 13 + j] = wf[(ch0 + c4) * 13 + j];
    wx[c4] = wr[c4 * 13 + 0] + wr[c4 * 13 + 7] + wr[c4 * 13 + 10];
    wy[c4] = wr[c4 * 13 + 1] + wr[c4 * 13 + 8] + wr[c4 * 13 + 11];
    wz[c4] = wr[c4 * 13 + 2] + wr[c4 * 13 + 9];
  }
  unsigned kp = *kp_p;

  // ---- phase 1: real pillars ----
  const unsigned NGRP = PIL_BLOCKS * 16;
  for (unsigned r = blockIdx.x * 16 + (tid >> 4); r < kp; r += NGRP) {
    uint4 ri = rowinfo[r];
    unsigned id = ri.x, start = ri.y, n = ri.z;
    int b = id / GXGY;
    unsigned rem = id - (unsigned)b * GXGY;
    int cx = rem / GYv;
    int cy = rem - cx * GYv;
    float gx = (float)cx * 0.2f + 0.1f;
    float gy = (float)cy * 0.2f + 0.1f - 40.0f;
    float mx = meanr[(size_t)r * 3 + 0];
    float my = meanr[(size_t)r * 3 + 1];
    float mz = meanr[(size_t)r * 3 + 2];
    float s0_[4];
#pragma unroll
    for (int c4 = 0; c4 < 4; c4++) {
      s0_[c4] = shv[c4] - wr[c4 * 13 + 7] * mx - wr[c4 * 13 + 8] * my
                        - wr[c4 * 13 + 9] * mz - wr[c4 * 13 + 10] * gx
                        - wr[c4 * 13 + 11] * gy;
    }
    float m0 = -3.4e38f, m1 = -3.4e38f, m2 = -3.4e38f, m3 = -3.4e38f;
    const float4* fb = (const float4*)(feat + (size_t)start * 8);
    for (unsigned p = 0; p < n; p++) {
      float4 A = fb[0], Bq = fb[1];
      fb += 2;
      int cz = (int)((A.z + 3.0f) / 4.0f);
      float fz = A.z - ((float)cz * 4.0f + 2.0f - 3.0f);
      float d0, d1, d2, d3;
#define DOT(dst, c4)                                                          \
      dst = s0_[c4];                                                          \
      dst += wx[c4] * A.x;            dst += wy[c4] * A.y;                    \
      dst += wz[c4] * A.z;            dst += wr[c4 * 13 + 3] * A.w;           \
      dst += wr[c4 * 13 + 4] * Bq.x;  dst += wr[c4 * 13 + 5] * Bq.y;          \
      dst += wr[c4 * 13 + 6] * Bq.z;  dst += wr[c4 * 13 + 12] * fz;
      DOT(d0, 0) DOT(d1, 1) DOT(d2, 2) DOT(d3, 3)
#undef DOT
      m0 = fmaxf(m0, d0); m1 = fmaxf(m1, d1);
      m2 = fmaxf(m2, d2); m3 = fmaxf(m3, d3);
    }
    float4 v = make_float4(fmaxf(m0, 0.f), fmaxf(m1, 0.f),
                           fmaxf(m2, 0.f), fmaxf(m3, 0.f));
    *(float4*)(out + (size_t)r * 64 + lane * 4) = v;
    if (lane == 0) {
      float* cc = out + (size_t)NSEG * 64 + (size_t)r * 3;
      cc[0] = (float)b;
      cc[1] = (float)cy;
      cc[2] = (float)cx;
    }
  }

  // ---- phase 2: empty rows — dense streaming zero-fill ----
  {
    const size_t gthreads = (size_t)PIL_BLOCKS * 256;
    size_t gid = (size_t)blockIdx.x * 256 + tid;
    size_t nempty = (size_t)(NSEG - kp);
    float4* zbase = (float4*)out + (size_t)kp * 16;   // 16 float4 per row
    float4 z4 = make_float4(0.f, 0.f, 0.f, 0.f);
    for (size_t j = gid; j < nempty * 16; j += gthreads) zbase[j] = z4;
    float* cbase = out + (size_t)NSEG * 64 + (size_t)kp * 3;
    for (size_t j = gid; j < nempty * 3; j += gthreads)
      cbase[j] = (j % 3 == 0) ? 4.0f : 0.0f;          // (b=4, cy=0, cx=0)
  }

  if (blockIdx.x == 0 && tid == 0) {
    float* g2 = out + (size_t)NSEG * 67;
    g2[0] = 400.0f;  // GY
    g2[1] = 352.0f;  // GX
  }
}

// ---------------- host launcher ----------------
extern "C" void kernel_launch(void* const* d_in, const int* in_sizes, int n_in,
                              void* d_out, int out_size, void* d_ws, size_t ws_size,
                              hipStream_t stream) {
  const float* pts = (const float*)d_in[0];
  const float* W   = (const float*)d_in[1];
  const float* g   = (const float*)d_in[2];
  const float* bta = (const float*)d_in[3];
  float* out = (float*)d_out;
  char* ws = (char*)d_ws;

  unsigned int* cnt  = (unsigned int*)(ws + O_CNT);
  float*        mom  = (float*)(ws + O_MOM);
  unsigned int* done = (unsigned int*)(ws + O_DONE);
  unsigned int* pptr = (unsigned int*)(ws + O_PPTR);
  uint4*        rowi = (uint4*)(ws + O_ROWI);
  float*        feat = (float*)(ws + O_FEAT);
  float*        mnr  = (float*)(ws + O_MEAN);
  unsigned int* bso  = (unsigned int*)(ws + O_BSO);
  unsigned int* bsc  = (unsigned int*)(ws + O_BSC);
  unsigned int* kp   = (unsigned int*)(ws + O_KP);
  float*        wf   = (float*)(ws + O_WF);
  float*        sh   = (float*)(ws + O_SH);
  (void)in_sizes; (void)n_in; (void)out_size; (void)ws_size;

  hipMemsetAsync(ws, 0, ZERO_BYTES, stream);   // cnt + mom + done

  k_count   <<<CNT_CHUNKS * 2, 256, 0, stream>>>(pts, cnt, mom);
  k_scan1   <<<NB_SCAN, 256, 0, stream>>>(cnt, bso, bsc);
  k_scan3   <<<NB_SCAN, 256, 0, stream>>>(cnt, bso, bsc, rowi, pptr, kp);
  k_sortfeat<<<NPTS / 256, 256, 0, stream>>>(pts, pptr, feat);
  k_pilcorr <<<PC_BLOCKS, 256, 0, stream>>>(rowi, feat, kp, mom, mnr, done, W, g, bta, wf, sh);
  k_pillar  <<<PIL_BLOCKS, 256, 0, stream>>>(wf, sh, rowi, kp, feat, mnr, out);
}

// Round 8
// 257.350 us; speedup vs baseline: 1.0704x; 1.0704x over previous
//
#include <hip/hip_runtime.h>
#include <stdint.h>
#include <utility>

// ---------------- problem constants ----------------
#define NPTS   262144      // 4 * 65536
#define GXGY   140800      // 352*400
#define GYv    400
#define NSEG   563201      // 4*GXGY + 1
#define SENT   563200
#define NB_SCAN 275        // 563200 / 2048
#define PIL_BLOCKS 2048    // persistent k_pillar grid
#define CNT_CHUNKS 512     // k_count chunks (512 points each); grid = 2x
#define PC_BLOCKS  512     // k_pilcorr grid

// ---------------- ws layout (bytes) ----------------
// Zeroed prefix: cnt + mom (one ~2.26 MB memset)
constexpr size_t alignup(size_t x) { return (x + 255) & ~(size_t)255; }
constexpr size_t O_CNT  = 0;                                   // NSEG u32 (zeroed)
constexpr size_t O_MOM  = alignup(O_CNT + (size_t)NSEG * 4);   // 104 f32 (zeroed)
constexpr size_t ZERO_BYTES = alignup(O_MOM + 104 * 4);
constexpr size_t O_PPTR = ZERO_BYTES;                          // NSEG u32 (sort cursor)
constexpr size_t O_ROWI = alignup(O_PPTR + (size_t)NSEG * 4);  // NPTS uint4 (rank -> id,start,n)
constexpr size_t O_FEAT = alignup(O_ROWI + (size_t)NPTS * 16); // NPTS*8 f32 (sorted raw feats)
constexpr size_t O_MEAN = alignup(O_FEAT + (size_t)NPTS * 32); // NPTS*3 f32 (per-rank mean)
constexpr size_t O_BSO  = alignup(O_MEAN + (size_t)NPTS * 12); // NB_SCAN u32 occ block sums
constexpr size_t O_BSC  = alignup(O_BSO + NB_SCAN * 4);        // NB_SCAN u32 cnt block sums
constexpr size_t O_KP   = alignup(O_BSC + NB_SCAN * 4);        // 1 u32 (#real pillars)
constexpr size_t O_WF   = alignup(O_KP + 256);                 // 832 f32: W*scale folded
constexpr size_t O_SH   = alignup(O_WF + 832 * 4);             // 64 f32: shift

// binning: mirror reference f32 arithmetic exactly (division, trunc, compares)
__device__ __forceinline__ int point_lin(float x, float y, int b, bool& mask) {
  float cxf = x / 0.2f;
  float cyf = (y + 40.0f) / 0.2f;
  int cx = (int)cxf, cy = (int)cyf;
  mask = (cxf >= 0.0f) && (cxf < 352.0f) && (cyf >= 0.0f) && (cyf < 400.0f);
  return mask ? (b * GXGY + cx * GYv + cy) : SENT;
}

// ---------------- K1: count + raw moments, template-split ----------------
// G=0 handles moment slots 0..32 + the cnt atomics; G=1 handles 33..64.
template<int LO, int NC, bool DOCNT>
__device__ __forceinline__ void count_body(const float* __restrict__ pts,
                                           unsigned int* __restrict__ cnt,
                                           float* __restrict__ mom,
                                           int chunk) {
  int tid = threadIdx.x;
  float acc[NC];
#pragma unroll
  for (int u = 0; u < NC; u++) acc[u] = 0.f;

  for (int rep = 0; rep < 2; rep++) {
    int i = chunk * 512 + rep * 256 + tid;
    const float* p = pts + (size_t)i * 7;
    float x = p[0], y = p[1], z = p[2];
    float w3 = p[3], w4 = p[4], w5 = p[5], w6 = p[6];
    if (DOCNT) {
      bool m;
      int lin = point_lin(x, y, i >> 16, m);
      atomicAdd(&cnt[lin], 1u);
    }
    int cx = (int)(x / 0.2f);
    int cy = (int)((y + 40.0f) / 0.2f);
    int cz = (int)((z + 3.0f) / 4.0f);
    float g[10] = {x, y, z, w3, w4, w5, w6,
                   x - ((float)cx * 0.2f + 0.1f + 0.0f),
                   y - ((float)cy * 0.2f + 0.1f - 40.0f),
                   z - ((float)cz * 4.0f + 2.0f - 3.0f)};
    int idx = 0;
#pragma unroll
    for (int q = 0; q < 10; q++) {
      if (idx >= LO && idx < LO + NC) acc[idx - LO] += g[q];
      idx++;
    }
#pragma unroll
    for (int pp = 0; pp < 10; pp++)
#pragma unroll
      for (int q = pp; q < 10; q++) {
        if (idx >= LO && idx < LO + NC) acc[idx - LO] += g[pp] * g[q];
        idx++;
      }
  }

  __shared__ float red[4][NC];
  int wv = tid >> 6, lane = tid & 63;
#pragma unroll
  for (int u = 0; u < NC; u++) {
    float v = acc[u];
    v += __shfl_xor(v, 1);  v += __shfl_xor(v, 2);  v += __shfl_xor(v, 4);
    v += __shfl_xor(v, 8);  v += __shfl_xor(v, 16); v += __shfl_xor(v, 32);
    if (lane == 0) red[wv][u] = v;
  }
  __syncthreads();
  int t = tid;
  if (t < 104 && !(t >= 7 && t <= 9)) {   // S1 u-slots come only from corrections
    int rix;
    if (t < 13) {
      rix = (t < 7) ? t : t - 3;          // phi: 10..12 -> 7..9 (c feats)
    } else {
      int u2 = t - 13, j = 0;
      while (u2 >= 13 - j) { u2 -= 13 - j; j++; }
      int k = j + u2;
      int a = (j < 7) ? j : (j < 10 ? j - 7 : j - 3);
      int b = (k < 7) ? k : (k < 10 ? k - 7 : k - 3);
      int lo = a < b ? a : b, hi = a < b ? b : a;
      rix = 10 + lo * (21 - lo) / 2 + (hi - lo);
    }
    if (rix >= LO && rix < LO + NC)
      atomicAdd(&mom[t], red[0][rix - LO] + red[1][rix - LO] +
                         red[2][rix - LO] + red[3][rix - LO]);
  }
}

__global__ __launch_bounds__(256) void k_count(const float* __restrict__ pts,
                                               unsigned int* __restrict__ cnt,
                                               float* __restrict__ mom) {
  int chunk = blockIdx.x >> 1;
  if ((blockIdx.x & 1) == 0) count_body<0, 33, true >(pts, cnt, mom, chunk);
  else                       count_body<33, 32, false>(pts, cnt, mom, chunk);
}

// ---------------- K2: per-block occupancy/count sums ----------------
__global__ __launch_bounds__(256) void k_scan1(const unsigned int* __restrict__ cnt,
                                               unsigned int* __restrict__ bso,
                                               unsigned int* __restrict__ bsc) {
  int t = threadIdx.x;
  int base = blockIdx.x * 2048 + t * 8;
  const uint4* c4 = (const uint4*)(cnt + base);
  uint4 a = c4[0], b = c4[1];
  unsigned so = (a.x > 0) + (a.y > 0) + (a.z > 0) + (a.w > 0) +
                (b.x > 0) + (b.y > 0) + (b.z > 0) + (b.w > 0);
  unsigned sc = a.x + a.y + a.z + a.w + b.x + b.y + b.z + b.w;
  for (int m = 1; m < 64; m <<= 1) { so += __shfl_xor(so, m); sc += __shfl_xor(sc, m); }
  __shared__ unsigned wo[4], wc[4];
  if ((t & 63) == 0) { wo[t >> 6] = so; wc[t >> 6] = sc; }
  __syncthreads();
  if (t == 0) {
    bso[blockIdx.x] = wo[0] + wo[1] + wo[2] + wo[3];
    bsc[blockIdx.x] = wc[0] + wc[1] + wc[2] + wc[3];
  }
}

// ---------------- K3: ranks + rowinfo + sort-cursor ----------------
__global__ __launch_bounds__(256) void k_scan3(const unsigned int* __restrict__ cnt,
                                               const unsigned int* __restrict__ bso,
                                               const unsigned int* __restrict__ bsc,
                                               uint4* __restrict__ rowinfo,
                                               unsigned int* __restrict__ pptr,
                                               unsigned int* __restrict__ kp) {
  int t = threadIdx.x;
  unsigned vo_m = 0, vc_m = 0, vo_a = 0;
  for (int e = t; e < NB_SCAN; e += 256) {
    unsigned o = bso[e], c = bsc[e];
    vo_a += o;
    if (e < (int)blockIdx.x) { vo_m += o; vc_m += c; }
  }
  for (int m = 1; m < 64; m <<= 1) {
    vo_m += __shfl_xor(vo_m, m);
    vc_m += __shfl_xor(vc_m, m);
    vo_a += __shfl_xor(vo_a, m);
  }
  __shared__ unsigned s0[4], s1[4], s2[4];
  int wv = t >> 6;
  if ((t & 63) == 0) { s0[wv] = vo_m; s1[wv] = vc_m; s2[wv] = vo_a; }
  __syncthreads();
  unsigned boo = s0[0] + s0[1] + s0[2] + s0[3];
  unsigned boc = s1[0] + s1[1] + s1[2] + s1[3];
  unsigned tot = s2[0] + s2[1] + s2[2] + s2[3];
  if (blockIdx.x == 0 && t == 0) *kp = tot;

  int base = blockIdx.x * 2048 + t * 8;
  const uint4* q = (const uint4*)(cnt + base);
  uint4 a = q[0], b = q[1];
  unsigned c[8] = {a.x, a.y, a.z, a.w, b.x, b.y, b.z, b.w};
  unsigned po[8], pc[8];
  unsigned so = 0, sc = 0;
#pragma unroll
  for (int k = 0; k < 8; k++) {
    po[k] = so; pc[k] = sc;
    so += (c[k] > 0); sc += c[k];
  }
  __shared__ unsigned sdo[256], sdc[256];
  __syncthreads();
  sdo[t] = so; sdc[t] = sc;
  __syncthreads();
  for (int off = 1; off < 256; off <<= 1) {
    unsigned ao = (t >= off) ? sdo[t - off] : 0u;
    unsigned ac = (t >= off) ? sdc[t - off] : 0u;
    __syncthreads();
    sdo[t] += ao; sdc[t] += ac;
    __syncthreads();
  }
  unsigned eo = sdo[t] - so + boo;
  unsigned ec = sdc[t] - sc + boc;
#pragma unroll
  for (int k = 0; k < 8; k++) {
    if (c[k] > 0) {
      unsigned r = eo + po[k];
      unsigned start = ec + pc[k];
      rowinfo[r] = make_uint4((unsigned)(base + k), start, c[k], 0u);
      pptr[base + k] = start;
    }
  }
}

// ---------------- K4: counting-sort of RAW features only (8 f32/row) ----------------
__global__ __launch_bounds__(256) void k_sortfeat(const float* __restrict__ pts,
                                                  unsigned int* __restrict__ pptr,
                                                  float* __restrict__ feat) {
  int i = blockIdx.x * 256 + threadIdx.x;
  if (i >= NPTS) return;
  const float* p = pts + (size_t)i * 7;
  float x = p[0], y = p[1], z = p[2];
  bool m;
  int lin = point_lin(x, y, i >> 16, m);
  if (lin == SENT) return;
  unsigned pos = atomicAdd(&pptr[lin], 1u);
  float4* fb = (float4*)(feat + (size_t)pos * 8);
  fb[0] = make_float4(x, y, z, p[3]);
  fb[1] = make_float4(p[4], p[5], p[6], 0.0f);
}

// ---------------- K5: per-pillar corrections + meanr (NO fence, NO BN tail) ----------------
// R8 change: the fused BN finalize (threadfence + done-counter, R2-R7) is
// suspected to cost ~20us — 2048 waves each executing a device-scope fence
// across 8 non-coherent XCD L2s. De-fused back to a separate k_bnfinal.
__global__ __launch_bounds__(256) void k_pilcorr(const uint4* __restrict__ rowinfo,
                                                 const float* __restrict__ feat,
                                                 const unsigned int* __restrict__ kpp,
                                                 float* __restrict__ mom,
                                                 float* __restrict__ meanr) {
  int tid = threadIdx.x;
  unsigned kp = *kpp;
  float cS1[3] = {0.f, 0.f, 0.f};
  float cAH[30], cUU[6];
#pragma unroll
  for (int u = 0; u < 30; u++) cAH[u] = 0.f;
#pragma unroll
  for (int u = 0; u < 6; u++) cUU[u] = 0.f;

  for (unsigned r = blockIdx.x * 256 + tid; r < kp; r += PC_BLOCKS * 256) {
    uint4 ri = rowinfo[r];
    unsigned start = ri.y, n = ri.z;
    const float4* fp = (const float4*)(feat + (size_t)start * 8);
    float S[10];
#pragma unroll
    for (int u = 0; u < 10; u++) S[u] = 0.f;
    for (unsigned p = 0; p < n; p++) {
      float4 A = fp[2 * p], Bq = fp[2 * p + 1];
      float x = A.x, y = A.y, z = A.z;
      int cx = (int)(x / 0.2f);
      int cy = (int)((y + 40.0f) / 0.2f);
      int cz = (int)((z + 3.0f) / 4.0f);
      S[0] += x; S[1] += y; S[2] += z; S[3] += A.w;
      S[4] += Bq.x; S[5] += Bq.y; S[6] += Bq.z;
      S[7] += x - ((float)cx * 0.2f + 0.1f + 0.0f);
      S[8] += y - ((float)cy * 0.2f + 0.1f - 40.0f);
      S[9] += z - ((float)cz * 4.0f + 2.0f - 3.0f);
    }
    float fn = (float)n;
    float mm[3] = {S[0] / fn, S[1] / fn, S[2] / fn};
    meanr[(size_t)r * 3 + 0] = mm[0];
    meanr[(size_t)r * 3 + 1] = mm[1];
    meanr[(size_t)r * 3 + 2] = mm[2];
    cS1[0] += S[0] - fn * mm[0];
    cS1[1] += S[1] - fn * mm[1];
    cS1[2] += S[2] - fn * mm[2];
#pragma unroll
    for (int a = 0; a < 3; a++)
#pragma unroll
      for (int h = 0; h < 10; h++) cAH[a * 10 + h] += mm[a] * S[h];
    int e = 0;
#pragma unroll
    for (int a = 0; a < 3; a++)
#pragma unroll
      for (int b = a; b < 3; b++) { cUU[e] += mm[a] * S[b]; e++; }
  }

  float vals[39];
#pragma unroll
  for (int u = 0; u < 3; u++)  vals[u] = cS1[u];
#pragma unroll
  for (int u = 0; u < 30; u++) vals[3 + u] = cAH[u];
#pragma unroll
  for (int u = 0; u < 6; u++)  vals[33 + u] = cUU[u];

  __shared__ float red[4][39];
  int wv = tid >> 6, lane = tid & 63;
#pragma unroll
  for (int u = 0; u < 39; u++) {
    float v = vals[u];
    v += __shfl_xor(v, 1);  v += __shfl_xor(v, 2);  v += __shfl_xor(v, 4);
    v += __shfl_xor(v, 8);  v += __shfl_xor(v, 16); v += __shfl_xor(v, 32);
    if (lane == 0) red[wv][u] = v;
  }
  __syncthreads();
  if (tid < 39) {
    float v = red[0][tid] + red[1][tid] + red[2][tid] + red[3][tid];
    int slot; float sign;
    if (tid < 3) {
      slot = 7 + tid; sign = 1.f;
    } else if (tid < 33) {
      int a = (tid - 3) / 10, h = (tid - 3) % 10;
      int hf = (h < 7) ? h : h + 3;
      int j = hf < 7 + a ? hf : 7 + a;
      int k = hf < 7 + a ? 7 + a : hf;
      slot = 13 + j * (27 - j) / 2 + (k - j);
      sign = -1.f;
    } else {
      int e = tid - 33;  // (0,0)(0,1)(0,2)(1,1)(1,2)(2,2)
      int a = (e < 3) ? 0 : (e < 5 ? 1 : 2);
      int b = (e < 3) ? e : (e < 5 ? e - 2 : 2);
      int j = 7 + a, k = 7 + b;
      slot = 13 + j * (27 - j) / 2 + (k - j);
      sign = -1.f;
    }
    atomicAdd(&mom[slot], sign * v);
  }
}

// ---------------- K6: finalize BN; fold scale into W (separate dispatch, R1-verified) ----------------
__global__ void k_bnfinal(const float* __restrict__ W,
                          const float* __restrict__ g,
                          const float* __restrict__ bta,
                          const float* __restrict__ mom,
                          float* __restrict__ wf,
                          float* __restrict__ sh) {
  int c = threadIdx.x;  // 64 threads
  float w[13];
#pragma unroll
  for (int j = 0; j < 13; j++) w[j] = W[c * 13 + j];
  const float invN = 1.0f / (float)NPTS;
  float mu = 0.f;
#pragma unroll
  for (int j = 0; j < 13; j++) mu += w[j] * (mom[j] * invN);
  float e2 = 0.f;
  int mi = 13;
#pragma unroll
  for (int j = 0; j < 13; j++) {
#pragma unroll
    for (int k = j; k < 13; k++) {
      float coef = (j == k) ? 1.0f : 2.0f;
      e2 += coef * w[j] * w[k] * mom[mi];
      mi++;
    }
  }
  e2 *= invN;
  float var = e2 - mu * mu;
  float rsig = 1.0f / sqrtf(var + 1e-3f);
  float sc = g[c] * rsig;
#pragma unroll
  for (int j = 0; j < 13; j++) wf[c * 13 + j] = w[j] * sc;
  sh[c] = bta[c] - mu * sc;
}

// ---------------- K7: per-pillar PFN + max, split real/empty phases ----------------
__global__ __launch_bounds__(256) void k_pillar(const float* __restrict__ wf,
                                                const float* __restrict__ sh,
                                                const uint4* __restrict__ rowinfo,
                                                const unsigned int* __restrict__ kp_p,
                                                const float* __restrict__ feat,
                                                const float* __restrict__ meanr,
                                                float* __restrict__ out) {
  int tid = threadIdx.x;
  int lane = tid & 15;
  int ch0 = lane * 4;
  float wr[52];
  float shv[4], wx[4], wy[4], wz[4];
#pragma unroll
  for (int c4 = 0; c4 < 4; c4++) {
    shv[c4] = sh[ch0 + c4];
#pragma unroll
    for (int j = 0; j < 13; j++) wr[c4 * 13 + j] = wf[(ch0 + c4) * 13 + j];
    wx[c4] = wr[c4 * 13 + 0] + wr[c4 * 13 + 7] + wr[c4 * 13 + 10];
    wy[c4] = wr[c4 * 13 + 1] + wr[c4 * 13 + 8] + wr[c4 * 13 + 11];
    wz[c4] = wr[c4 * 13 + 2] + wr[c4 * 13 + 9];
  }
  unsigned kp = *kp_p;

  // ---- phase 1: real pillars ----
  const unsigned NGRP = PIL_BLOCKS * 16;
  for (unsigned r = blockIdx.x * 16 + (tid >> 4); r < kp; r += NGRP) {
    uint4 ri = rowinfo[r];
    unsigned id = ri.x, start = ri.y, n = ri.z;
    int b = id / GXGY;
    unsigned rem = id - (unsigned)b * GXGY;
    int cx = rem / GYv;
    int cy = rem - cx * GYv;
    float gx = (float)cx * 0.2f + 0.1f;
    float gy = (float)cy * 0.2f + 0.1f - 40.0f;
    float mx = meanr[(size_t)r * 3 + 0];
    float my = meanr[(size_t)r * 3 + 1];
    float mz = meanr[(size_t)r * 3 + 2];
    float s0_[4];
#pragma unroll
    for (int c4 = 0; c4 < 4; c4++) {
      s0_[c4] = shv[c4] - wr[c4 * 13 + 7] * mx - wr[c4 * 13 + 8] * my
                        - wr[c4 * 13 + 9] * mz - wr[c4 * 13 + 10] * gx
                        - wr[c4 * 13 + 11] * gy;
    }
    float m0 = -3.4e38f, m1 = -3.4e38f, m2 = -3.4e38f, m3 = -3.4e38f;
    const float4* fb = (const float4*)(feat + (size_t)start * 8);
    for (unsigned p = 0; p < n; p++) {
      float4 A = fb[0], Bq = fb[1];
      fb += 2;
      int cz = (int)((A.z + 3.0f) / 4.0f);
      float fz = A.z - ((float)cz * 4.0f + 2.0f - 3.0f);
      float d0, d1, d2, d3;
#define DOT(dst, c4)                                                          \
      dst = s0_[c4];                                                          \
      dst += wx[c4] * A.x;            dst += wy[c4] * A.y;                    \
      dst += wz[c4] * A.z;            dst += wr[c4 * 13 + 3] * A.w;           \
      dst += wr[c4 * 13 + 4] * Bq.x;  dst += wr[c4 * 13 + 5] * Bq.y;          \
      dst += wr[c4 * 13 + 6] * Bq.z;  dst += wr[c4 * 13 + 12] * fz;
      DOT(d0, 0) DOT(d1, 1) DOT(d2, 2) DOT(d3, 3)
#undef DOT
      m0 = fmaxf(m0, d0); m1 = fmaxf(m1, d1);
      m2 = fmaxf(m2, d2); m3 = fmaxf(m3, d3);
    }
    float4 v = make_float4(fmaxf(m0, 0.f), fmaxf(m1, 0.f),
                           fmaxf(m2, 0.f), fmaxf(m3, 0.f));
    *(float4*)(out + (size_t)r * 64 + lane * 4) = v;
    if (lane == 0) {
      float* cc = out + (size_t)NSEG * 64 + (size_t)r * 3;
      cc[0] = (float)b;
      cc[1] = (float)cy;
      cc[2] = (float)cx;
    }
  }

  // ---- phase 2: empty rows — dense streaming zero-fill ----
  {
    const size_t gthreads = (size_t)PIL_BLOCKS * 256;
    size_t gid = (size_t)blockIdx.x * 256 + tid;
    size_t nempty = (size_t)(NSEG - kp);
    float4* zbase = (float4*)out + (size_t)kp * 16;   // 16 float4 per row
    float4 z4 = make_float4(0.f, 0.f, 0.f, 0.f);
    for (size_t j = gid; j < nempty * 16; j += gthreads) zbase[j] = z4;
    float* cbase = out + (size_t)NSEG * 64 + (size_t)kp * 3;
    for (size_t j = gid; j < nempty * 3; j += gthreads)
      cbase[j] = (j % 3 == 0) ? 4.0f : 0.0f;          // (b=4, cy=0, cx=0)
  }

  if (blockIdx.x == 0 && tid == 0) {
    float* g2 = out + (size_t)NSEG * 67;
    g2[0] = 400.0f;  // GY
    g2[1] = 352.0f;  // GX
  }
}

// ---------------- host launcher ----------------
extern "C" void kernel_launch(void* const* d_in, const int* in_sizes, int n_in,
                              void* d_out, int out_size, void* d_ws, size_t ws_size,
                              hipStream_t stream) {
  const float* pts = (const float*)d_in[0];
  const float* W   = (const float*)d_in[1];
  const float* g   = (const float*)d_in[2];
  const float* bta = (const float*)d_in[3];
  float* out = (float*)d_out;
  char* ws = (char*)d_ws;

  unsigned int* cnt  = (unsigned int*)(ws + O_CNT);
  float*        mom  = (float*)(ws + O_MOM);
  unsigned int* pptr = (unsigned int*)(ws + O_PPTR);
  uint4*        rowi = (uint4*)(ws + O_ROWI);
  float*        feat = (float*)(ws + O_FEAT);
  float*        mnr  = (float*)(ws + O_MEAN);
  unsigned int* bso  = (unsigned int*)(ws + O_BSO);
  unsigned int* bsc  = (unsigned int*)(ws + O_BSC);
  unsigned int* kp   = (unsigned int*)(ws + O_KP);
  float*        wf   = (float*)(ws + O_WF);
  float*        sh   = (float*)(ws + O_SH);
  (void)in_sizes; (void)n_in; (void)out_size; (void)ws_size;

  hipMemsetAsync(ws, 0, ZERO_BYTES, stream);   // cnt + mom

  k_count   <<<CNT_CHUNKS * 2, 256, 0, stream>>>(pts, cnt, mom);
  k_scan1   <<<NB_SCAN, 256, 0, stream>>>(cnt, bso, bsc);
  k_scan3   <<<NB_SCAN, 256, 0, stream>>>(cnt, bso, bsc, rowi, pptr, kp);
  k_sortfeat<<<NPTS / 256, 256, 0, stream>>>(pts, pptr, feat);
  k_pilcorr <<<PC_BLOCKS, 256, 0, stream>>>(rowi, feat, kp, mom, mnr);
  k_bnfinal <<<1, 64, 0, stream>>>(W, g, bta, mom, wf, sh);
  k_pillar  <<<PIL_BLOCKS, 256, 0, stream>>>(wf, sh, rowi, kp, feat, mnr, out);
}